// Round 8
// baseline (251.549 us; speedup 1.0000x reference)
//
#include <hip/hip_runtime.h>

#define BATCH 4
#define SEQ   4096
#define DIM   1024
#define EPS_F 1e-6f
#define KSPLIT 4

typedef __bf16 bf16_t;
typedef bf16_t bf16x8 __attribute__((ext_vector_type(8)));
typedef float  f32x4  __attribute__((ext_vector_type(4)));
typedef unsigned short u16x8 __attribute__((ext_vector_type(8)));

__device__ __forceinline__ unsigned short f2bf(float f) {
  unsigned u = __float_as_uint(f);
  u += 0x7FFFu + ((u >> 16) & 1u);          // round-to-nearest-even
  return (unsigned short)(u >> 16);
}
__device__ __forceinline__ float bf2f(unsigned short h) {
  return __uint_as_float(((unsigned)h) << 16);
}
__device__ __forceinline__ float phi_f(float x) {
  return x > 0.f ? x + 1.f : __expf(x);     // elu(x)+1
}

__global__ __launch_bounds__(256) void zero_f32(float* __restrict__ p, int n) {
  const int i = blockIdx.x * 256 + threadIdx.x;
  if (i < n) p[i] = 0.f;
}

// ---- transpose (+ optional phi, optional fused column-sum) ----
template<bool PHI, bool KSUM>
__global__ __launch_bounds__(256) void phi_transpose(const float* __restrict__ in,
    unsigned short* __restrict__ out, float* __restrict__ ksum, int rows, int cols) {
  __shared__ float t[32][33];
  __shared__ float ps[8][32];
  const int bx = blockIdx.x * 32;          // col base
  const int by = blockIdx.y * 32;          // row base
  const size_t bo = (size_t)blockIdx.z * rows * cols;
  const int x = threadIdx.x, y = threadIdx.y;
  #pragma unroll
  for (int j = 0; j < 32; j += 8) {
    float v = in[bo + (size_t)(by + y + j) * cols + bx + x];
    if (PHI) v = phi_f(v);
    t[y + j][x] = v;
  }
  __syncthreads();
  #pragma unroll
  for (int j = 0; j < 32; j += 8)
    out[bo + (size_t)(bx + y + j) * rows + by + x] = f2bf(t[x][y + j]);
  if (KSUM) {
    float s = t[y][x] + t[y + 8][x] + t[y + 16][x] + t[y + 24][x];
    ps[y][x] = s;
    __syncthreads();
    if (y == 0) {
      float tot = 0.f;
      #pragma unroll
      for (int j = 0; j < 8; ++j) tot += ps[j][x];
      atomicAdd(&ksum[(size_t)blockIdx.z * cols + bx + x], tot);
    }
  }
}

// ---- reduce KSPLIT bf16 partials -> bf16 KVt ----
__global__ __launch_bounds__(256) void reduce_kv(const unsigned short* __restrict__ P,
    unsigned short* __restrict__ KVt) {
  const size_t per = (size_t)DIM * DIM;
  const size_t i = ((size_t)blockIdx.x * 256 + threadIdx.x) * 8;
  const size_t b = blockIdx.y;
  const unsigned short* p = P + b * KSPLIT * per + i;
  float s[8] = {};
  #pragma unroll
  for (int sp = 0; sp < KSPLIT; ++sp) {
    u16x8 v = *(const u16x8*)(p + sp * per);
    #pragma unroll
    for (int j = 0; j < 8; ++j) s[j] += bf2f(v[j]);
  }
  u16x8 o;
  #pragma unroll
  for (int j = 0; j < 8; ++j) o[j] = f2bf(s[j]);
  *(u16x8*)(KVt + b * per + i) = o;
}

#define GLD(gp, lp) __builtin_amdgcn_global_load_lds( \
    (const __attribute__((address_space(1))) unsigned int*)(gp), \
    (__attribute__((address_space(3))) unsigned int*)(lp), 16, 0, 0)
#define BARRIER __builtin_amdgcn_s_barrier()
#define WAITV(n) asm volatile("s_waitcnt vmcnt(" #n ")" ::: "memory")
#define LGK(n)   asm volatile("s_waitcnt lgkmcnt(" #n ")" ::: "memory")

// ======== gemm1: 256x256 8-phase bt-GEMM, bf16 in (R5 structure, best) ======
template<int EPI, int KS, int NT>
__global__ __launch_bounds__(512, 2) void gemm256_bt(
    const unsigned short* __restrict__ A, const unsigned short* __restrict__ Bm,
    void* __restrict__ Cv, const float* __restrict__ invZ,
    int M, int Nc, int K, int gx, int gy) {
  extern __shared__ unsigned short lds[];
  unsigned short* const As0 = lds;
  unsigned short* const As1 = lds + 16384;
  unsigned short* const Bs0 = lds + 32768;
  unsigned short* const Bs1 = lds + 49152;

  const int t    = threadIdx.x;
  const int wid  = t >> 6;
  const int lane = t & 63;
  const int id   = blockIdx.x;
  const int sw   = (id & 7) * (gridDim.x >> 3) + (id >> 3);
  const int bxi  = sw % gx;
  const int rem  = sw / gx;
  const int byi  = rem % gy;
  const int bz   = rem / gy;
  const int brow = byi * 256, bcol = bxi * 256;
  const size_t batch = bz / KS;
  const int split = bz % KS;
  const int Kc = K / KS;
  const unsigned short* Ab = A + batch * ((size_t)M * K) + (size_t)brow * K + (size_t)split * Kc;
  const unsigned short* Bb = Bm + batch * ((size_t)Nc * K) + (size_t)bcol * K + (size_t)split * Kc;

  const int srow_t = t >> 3;
  const int c_src  = (t & 7) ^ (srow_t & 7);
  const unsigned short* gA = Ab + (size_t)srow_t * K + c_src * 8;
  const unsigned short* gB = Bb + (size_t)((srow_t >> 5) * 64 + (srow_t & 31)) * K + c_src * 8;
  const int ldsAu = wid * 512;
  const int ldsBu = wid * 512 + (wid >> 2) * 2048;

  auto stageA = [&](unsigned short* D, int h, int kt) {
    GLD(gA + (size_t)(h * 64) * K + (size_t)kt * 64,       D + (h * 64) * 64 + ldsAu);
    GLD(gA + (size_t)(128 + h * 64) * K + (size_t)kt * 64, D + (128 + h * 64) * 64 + ldsAu);
  };
  auto stageB = [&](unsigned short* D, int h, int kt) {
    GLD(gB + (size_t)(h * 32) * K + (size_t)kt * 64,       D + (h * 32) * 64 + ldsBu);
    GLD(gB + (size_t)(128 + h * 32) * K + (size_t)kt * 64, D + (128 + h * 32) * 64 + ldsBu);
  };

  const int fr  = lane & 15;
  const int g   = lane >> 4;
  const int wrw = (wid >> 2) * 128;
  const int wcw = (wid & 3) * 64;
  const int ck0 = ((g)     ^ (fr & 7)) * 8;
  const int ck1 = ((4 + g) ^ (fr & 7)) * 8;

  f32x4 acc[8][4] = {};
  bf16x8 afX[4][2], afY[4][2], bfX[2][2], bfY[2][2];

#define LDA(S, mh, DST) { _Pragma("unroll") for (int m_ = 0; m_ < 4; ++m_) { \
    const int ro_ = (wrw + ((mh) * 4 + m_) * 16 + fr) * 64; \
    DST[m_][0] = *(const bf16x8*)((S) + ro_ + ck0); \
    DST[m_][1] = *(const bf16x8*)((S) + ro_ + ck1); } }
#define LDBF(S, nh, DST) { _Pragma("unroll") for (int n_ = 0; n_ < 2; ++n_) { \
    const int ro_ = (wcw + (nh) * 32 + n_ * 16 + fr) * 64; \
    DST[n_][0] = *(const bf16x8*)((S) + ro_ + ck0); \
    DST[n_][1] = *(const bf16x8*)((S) + ro_ + ck1); } }
#define MM(mh, nh, AF, BF) { __builtin_amdgcn_s_setprio(1); \
    _Pragma("unroll") for (int m_ = 0; m_ < 4; ++m_) \
    _Pragma("unroll") for (int n_ = 0; n_ < 2; ++n_) \
    _Pragma("unroll") for (int k_ = 0; k_ < 2; ++k_) \
      acc[(mh) * 4 + m_][(nh) * 2 + n_] = __builtin_amdgcn_mfma_f32_16x16x32_bf16( \
          AF[m_][k_], BF[n_][k_], acc[(mh) * 4 + m_][(nh) * 2 + n_], 0, 0, 0); \
    __builtin_amdgcn_s_setprio(0); }

  unsigned short *Ac = As0, *An = As1, *Bc = Bs0, *Bn = Bs1;

  stageA(Ac, 0, 0); stageB(Bc, 0, 0); stageB(Bc, 1, 0); stageA(Ac, 1, 0);
  stageA(An, 0, 1); stageB(Bn, 0, 1); stageB(Bn, 1, 1);
  stageA(An, 1, 1);
  WAITV(8);
  BARRIER;
  LDA(Ac, 0, afX); LDBF(Bc, 0, bfX);

  #pragma unroll 1
  for (int it = 0; it < NT - 2; ++it) {
    const int t2 = it + 2;
    LDBF(Bc, 1, bfY);
    stageA(Ac, 0, t2);
    BARRIER; MM(0, 0, afX, bfX); BARRIER;
    stageB(Bc, 0, t2);
    WAITV(6);
    BARRIER;
    LDA(Ac, 1, afY);
    MM(0, 1, afX, bfY); BARRIER;
    LDA(An, 0, afX);
    stageB(Bc, 1, t2);
    BARRIER; MM(1, 0, afY, bfX); BARRIER;
    LDBF(Bn, 0, bfX);
    stageA(Ac, 1, t2);
    BARRIER; MM(1, 1, afY, bfY); BARRIER;
    unsigned short* tp;
    tp = Ac; Ac = An; An = tp;
    tp = Bc; Bc = Bn; Bn = tp;
  }
  LDBF(Bc, 1, bfY);
  BARRIER; MM(0, 0, afX, bfX); BARRIER;
  WAITV(0);
  BARRIER;
  LDA(Ac, 1, afY);
  MM(0, 1, afX, bfY); BARRIER;
  LDA(An, 0, afX);
  BARRIER; MM(1, 0, afY, bfX); BARRIER;
  LDBF(Bn, 0, bfX);
  BARRIER; MM(1, 1, afY, bfY); BARRIER;
  {
    unsigned short* tp;
    tp = Ac; Ac = An; An = tp;
    tp = Bc; Bc = Bn; Bn = tp;
  }
  LDBF(Bc, 1, bfY);
  BARRIER; MM(0, 0, afX, bfX);
  LDA(Ac, 1, afY);
  MM(0, 1, afX, bfY);
  MM(1, 0, afY, bfX);
  MM(1, 1, afY, bfY);
#undef LDA
#undef LDBF
#undef MM

  if (EPI == 0) {
    unsigned short* Cb = (unsigned short*)Cv + (size_t)bz * M * Nc;
    #pragma unroll
    for (int m = 0; m < 8; ++m) {
      const int row = brow + wrw + m * 16 + g * 4;
      #pragma unroll
      for (int r = 0; r < 4; ++r)
        #pragma unroll
        for (int n = 0; n < 4; ++n)
          Cb[(size_t)(row + r) * Nc + bcol + wcw + n * 16 + fr] = f2bf(acc[m][n][r]);
    }
  } else {
    float* Cb = (float*)Cv + batch * ((size_t)M * Nc);
    const float* zb = invZ + batch * (size_t)M;
    #pragma unroll
    for (int m = 0; m < 8; ++m) {
      const int row = brow + wrw + m * 16 + g * 4;
      #pragma unroll
      for (int r = 0; r < 4; ++r) {
        const float z = zb[row + r];
        #pragma unroll
        for (int n = 0; n < 4; ++n)
          Cb[(size_t)(row + r) * Nc + bcol + wcw + n * 16 + fr] = acc[m][n][r] * z;
      }
    }
  }
}

// ======= gemm2f: fused out = (phi(Q) * KVt^T) / Z, Q fp32 direct ===========
// A = Q fp32 reg-staged (issue phase p, phi+cvt+ds_write at p+1 MFMA segment);
// B = KVt via global_load_lds (unchanged R4 cadence). Z computed in-kernel:
// per-thread partials vs LDS-resident Ksum, LDS tree-reduce after K-loop.
__global__ __launch_bounds__(512, 1) void gemm2f(
    const float* __restrict__ Qf, const unsigned short* __restrict__ Bm,
    float* __restrict__ C, const float* __restrict__ KsumG) {
  extern __shared__ unsigned short lds[];
  unsigned short* const As0 = lds;
  unsigned short* const As1 = lds + 16384;
  unsigned short* const Bs0 = lds + 32768;
  unsigned short* const Bs1 = lds + 49152;
  float* const ksumL = (float*)(lds + 65536);          // [1024] f32 (4 KB)
  float* const zbuf  = (float*)(lds + 32768);          // overlay Bs0 after loop
  float* const zfin  = ((float*)(lds + 32768)) + 2048; // overlay Bs0+8KB

  const int t    = threadIdx.x;
  const int wid  = t >> 6;
  const int lane = t & 63;
  const int id   = blockIdx.x;
  const int sw   = (id & 7) * (gridDim.x >> 3) + (id >> 3);
  const int bxi  = sw % 4;             // gx = 4
  const int rem  = sw / 4;
  const int byi  = rem % 16;           // gy = 16
  const int bz   = rem / 16;           // batch
  const int brow = byi * 256, bcol = bxi * 256;
  const float*          Ab = Qf + (size_t)bz * SEQ * DIM + (size_t)brow * DIM;
  const unsigned short* Bb = Bm + (size_t)bz * DIM * DIM + (size_t)bcol * DIM;

  const int srow  = t >> 3;
  const int c_src = (t & 7) ^ (srow & 7);
  const float* gQ = Ab + (size_t)srow * DIM + c_src * 8;
  const unsigned short* gB = Bb + (size_t)((srow >> 5) * 64 + (srow & 31)) * DIM + c_src * 8;
  const int ldsBu = wid * 512 + (wid >> 2) * 2048;
  const int aoff  = srow * 64 + (t & 7) * 8;   // this thread's A-slot (elems)

  auto stageB = [&](unsigned short* D, int h, int kt) {
    GLD(gB + (size_t)(h * 32) * DIM + (size_t)kt * 64,       D + (h * 32) * 64 + ldsBu);
    GLD(gB + (size_t)(128 + h * 32) * DIM + (size_t)kt * 64, D + (128 + h * 32) * 64 + ldsBu);
  };

  const int fr  = lane & 15;
  const int g   = lane >> 4;
  const int wrw = (wid >> 2) * 128;
  const int wcw = (wid & 3) * 64;
  const int ck0 = ((g)     ^ (fr & 7)) * 8;
  const int ck1 = ((4 + g) ^ (fr & 7)) * 8;

  f32x4 acc[8][4] = {};
  bf16x8 af[4][2], bf0[2][2], bf1[2][2];
  float4 sA0, sA1, sA2, sA3, sB0, sB1, sB2, sB3;
  float zp0 = 0.f, zp1 = 0.f, zp2 = 0.f, zp3 = 0.f;

#define LOADA(S, mh) { _Pragma("unroll") for (int m_ = 0; m_ < 4; ++m_) { \
    const int ro_ = (wrw + ((mh) * 4 + m_) * 16 + fr) * 64; \
    af[m_][0] = *(const bf16x8*)((S) + ro_ + ck0); \
    af[m_][1] = *(const bf16x8*)((S) + ro_ + ck1); } }
#define LOADB(S, nh, BF) { _Pragma("unroll") for (int n_ = 0; n_ < 2; ++n_) { \
    const int ro_ = (wcw + (nh) * 32 + n_ * 16 + fr) * 64; \
    BF[n_][0] = *(const bf16x8*)((S) + ro_ + ck0); \
    BF[n_][1] = *(const bf16x8*)((S) + ro_ + ck1); } }
#define QUAD(mh, nh, BF) { __builtin_amdgcn_s_setprio(1); \
    _Pragma("unroll") for (int m_ = 0; m_ < 4; ++m_) \
    _Pragma("unroll") for (int n_ = 0; n_ < 2; ++n_) \
    _Pragma("unroll") for (int k_ = 0; k_ < 2; ++k_) \
      acc[(mh) * 4 + m_][(nh) * 2 + n_] = __builtin_amdgcn_mfma_f32_16x16x32_bf16( \
          af[m_][k_], BF[n_][k_], acc[(mh) * 4 + m_][(nh) * 2 + n_], 0, 0, 0); \
    __builtin_amdgcn_s_setprio(0); }
#define ISSUEQ(P, h, kt) { \
    P##0 = *(const float4*)(gQ + (size_t)((h) * 64) * DIM + (kt) * 64); \
    P##1 = *(const float4*)(gQ + (size_t)((h) * 64) * DIM + (kt) * 64 + 4); \
    P##2 = *(const float4*)(gQ + (size_t)((h) * 64 + 128) * DIM + (kt) * 64); \
    P##3 = *(const float4*)(gQ + (size_t)((h) * 64 + 128) * DIM + (kt) * 64 + 4); }
#define CVT8(VA, VB, OUT, ZP, K0, K1) { u16x8 o_; float q_; \
    o_[0] = f2bf(phi_f(VA.x)); q_ = bf2f(o_[0]); ZP += q_ * K0.x; \
    o_[1] = f2bf(phi_f(VA.y)); q_ = bf2f(o_[1]); ZP += q_ * K0.y; \
    o_[2] = f2bf(phi_f(VA.z)); q_ = bf2f(o_[2]); ZP += q_ * K0.z; \
    o_[3] = f2bf(phi_f(VA.w)); q_ = bf2f(o_[3]); ZP += q_ * K0.w; \
    o_[4] = f2bf(phi_f(VB.x)); q_ = bf2f(o_[4]); ZP += q_ * K1.x; \
    o_[5] = f2bf(phi_f(VB.y)); q_ = bf2f(o_[5]); ZP += q_ * K1.y; \
    o_[6] = f2bf(phi_f(VB.z)); q_ = bf2f(o_[6]); ZP += q_ * K1.z; \
    o_[7] = f2bf(phi_f(VB.w)); q_ = bf2f(o_[7]); ZP += q_ * K1.w; \
    OUT = o_; }
#define COMMITQ(P, D, h, kt, ZA, ZB) { \
    float4 kv0 = *(const float4*)(ksumL + (kt) * 64 + c_src * 8); \
    float4 kv1 = *(const float4*)(ksumL + (kt) * 64 + c_src * 8 + 4); \
    u16x8 w0, w1; \
    CVT8(P##0, P##1, w0, ZA, kv0, kv1); \
    CVT8(P##2, P##3, w1, ZB, kv0, kv1); \
    *(u16x8*)((D) + ((h) * 64) * 64 + aoff)         = w0; \
    *(u16x8*)((D) + ((h) * 64 + 128) * 64 + aoff)   = w1; }

  // ---- ksum -> LDS ----
  if (t < 128) {
    float4 k0 = *(const float4*)(KsumG + (size_t)bz * DIM + t * 8);
    float4 k1 = *(const float4*)(KsumG + (size_t)bz * DIM + t * 8 + 4);
    *(float4*)(ksumL + t * 8) = k0;
    *(float4*)(ksumL + t * 8 + 4) = k1;
  }
  __syncthreads();

  // ---- prologue: tile0 A committed, B0/B1 staged, tile1 A.h0 committed ----
  ISSUEQ(sA, 0, 0);
  ISSUEQ(sB, 1, 0);
  stageB(Bs0, 0, 0); stageB(Bs0, 1, 0);
  COMMITQ(sA, As0, 0, 0, zp0, zp2);
  COMMITQ(sB, As0, 1, 0, zp1, zp3);
  ISSUEQ(sA, 0, 1);
  stageB(Bs1, 0, 1); stageB(Bs1, 1, 1);
  COMMITQ(sA, As1, 0, 1, zp0, zp2);
  LGK(0);
  BARRIER;

  #pragma unroll 1
  for (int i = 0; i < 7; ++i) {
    const int k2 = 2 * i;
    // ph1
    LOADA(As0, 0); LOADB(Bs0, 0, bf0); ISSUEQ(sA, 1, k2 + 1);
    BARRIER; QUAD(0, 0, bf0); BARRIER;
    // ph2 (+commit sA -> As1.h1 tile k+1)
    LOADB(Bs0, 1, bf1); ISSUEQ(sB, 0, k2 + 2);
    BARRIER; QUAD(0, 1, bf1);
    COMMITQ(sA, As1, 1, k2 + 1, zp1, zp3); LGK(0); BARRIER;
    // ph3 (+commit sB -> As0.h0 tile k+2)
    LOADA(As0, 1); stageB(Bs0, 0, k2 + 2);
    BARRIER; QUAD(1, 0, bf0);
    COMMITQ(sB, As0, 0, k2 + 2, zp0, zp2); LGK(0); BARRIER;
    // ph4
    stageB(Bs0, 1, k2 + 2);
    BARRIER; QUAD(1, 1, bf1); BARRIER;
    // ph5
    LOADA(As1, 0); LOADB(Bs1, 0, bf0); ISSUEQ(sA, 1, k2 + 2);
    BARRIER; QUAD(0, 0, bf0); BARRIER;
    // ph6 (+commit sA -> As0.h1 tile k+2)
    LOADB(Bs1, 1, bf1); ISSUEQ(sB, 0, k2 + 3);
    BARRIER; QUAD(0, 1, bf1);
    COMMITQ(sA, As0, 1, k2 + 2, zp1, zp3); LGK(0); BARRIER;
    // ph7 (+commit sB -> As1.h0 tile k+3)
    LOADA(As1, 1); stageB(Bs1, 0, k2 + 3);
    BARRIER; QUAD(1, 0, bf0);
    COMMITQ(sB, As1, 0, k2 + 3, zp0, zp2); LGK(0); BARRIER;
    // ph8
    stageB(Bs1, 1, k2 + 3);
    BARRIER; QUAD(1, 1, bf1); BARRIER;
  }
  { // tail iteration: tiles 14,15; only t15.A.h1 left to stage
    LOADA(As0, 0); LOADB(Bs0, 0, bf0); ISSUEQ(sA, 1, 15);
    BARRIER; QUAD(0, 0, bf0); BARRIER;
    LOADB(Bs0, 1, bf1);
    BARRIER; QUAD(0, 1, bf1);
    COMMITQ(sA, As1, 1, 15, zp1, zp3); LGK(0); BARRIER;
    LOADA(As0, 1);
    BARRIER; QUAD(1, 0, bf0); BARRIER;
    BARRIER; QUAD(1, 1, bf1); BARRIER;
    LOADA(As1, 0); LOADB(Bs1, 0, bf0);
    BARRIER; QUAD(0, 0, bf0); BARRIER;
    LOADB(Bs1, 1, bf1);
    BARRIER; QUAD(0, 1, bf1); BARRIER;
    LOADA(As1, 1);
    BARRIER; QUAD(1, 0, bf0); BARRIER;
    QUAD(1, 1, bf1);
  }
#undef LOADA
#undef LOADB
#undef QUAD
#undef ISSUEQ
#undef CVT8
#undef COMMITQ

  // ---- Z reduce (overlay on Bs0; all B reads are long done) ----
  BARRIER;
  zbuf[(srow)       * 8 + (t & 7)] = zp0;
  zbuf[(srow + 64)  * 8 + (t & 7)] = zp1;
  zbuf[(srow + 128) * 8 + (t & 7)] = zp2;
  zbuf[(srow + 192) * 8 + (t & 7)] = zp3;
  LGK(0);
  BARRIER;
  if (t < 256) {
    float4 a = *(const float4*)(zbuf + t * 8);
    float4 b = *(const float4*)(zbuf + t * 8 + 4);
    const float s = a.x + a.y + a.z + a.w + b.x + b.y + b.z + b.w;
    zfin[t] = 1.0f / (s + EPS_F);
  }
  LGK(0);
  BARRIER;

  // ---- epilogue ----
  float* Cb = C + (size_t)bz * SEQ * DIM;
  #pragma unroll
  for (int m = 0; m < 8; ++m) {
    const int rl = wrw + m * 16 + g * 4;
    #pragma unroll
    for (int r = 0; r < 4; ++r) {
      const float z = zfin[rl + r];
      const int row = brow + rl + r;
      #pragma unroll
      for (int n = 0; n < 4; ++n)
        Cb[(size_t)row * DIM + bcol + wcw + n * 16 + fr] = acc[m][n][r] * z;
    }
  }
}

extern "C" void kernel_launch(void* const* d_in, const int* in_sizes, int n_in,
                              void* d_out, int out_size, void* d_ws, size_t ws_size,
                              hipStream_t stream) {
  const float* Q = (const float*)d_in[0];
  const float* K = (const float*)d_in[1];
  const float* V = (const float*)d_in[2];
  float* out = (float*)d_out;

  char* ws = (char*)d_ws;
  size_t off = 0;
  auto alloc = [&](size_t bytes) {
    void* p = ws + off;
    off += (bytes + 255) & ~(size_t)255;
    return p;
  };
  unsigned short* P    = (unsigned short*)alloc((size_t)BATCH * KSPLIT * DIM * DIM * 2);
  unsigned short* Kt   = (unsigned short*)alloc((size_t)BATCH * SEQ * DIM * 2);
  unsigned short* Vt   = (unsigned short*)alloc((size_t)BATCH * SEQ * DIM * 2);
  unsigned short* KVt  = (unsigned short*)alloc((size_t)BATCH * DIM * DIM * 2);
  float* Ksum = (float*)alloc((size_t)BATCH * DIM * 4);

  hipFuncSetAttribute(reinterpret_cast<const void*>(&gemm256_bt<0, KSPLIT, 16>),
                      hipFuncAttributeMaxDynamicSharedMemorySize, 131072);
  hipFuncSetAttribute(reinterpret_cast<const void*>(&gemm2f),
                      hipFuncAttributeMaxDynamicSharedMemorySize, 135168);

  const dim3 tb(32, 8);
  zero_f32<<<(BATCH * DIM + 255) / 256, 256, 0, stream>>>(Ksum, BATCH * DIM);
  phi_transpose<true, true ><<<dim3(DIM / 32, SEQ / 32, BATCH), tb, 0, stream>>>(K, Kt, Ksum, SEQ, DIM);
  phi_transpose<false, false><<<dim3(DIM / 32, SEQ / 32, BATCH), tb, 0, stream>>>(V, Vt, nullptr, SEQ, DIM);
  // gemm1 split-K: P[b][s] = Vt * Kt^T over n-split s   (M=Nc=1024, Kc=1024 -> NT=16)
  gemm256_bt<0, KSPLIT, 16><<<(DIM / 256) * (DIM / 256) * BATCH * KSPLIT, 512, 131072, stream>>>(
      Vt, Kt, P, nullptr, DIM, DIM, SEQ, DIM / 256, DIM / 256);
  reduce_kv<<<dim3(DIM * DIM / (256 * 8), BATCH), 256, 0, stream>>>(P, KVt);
  // gemm2 fused: out = (phi(Q) * KVt^T) / Z, Q fp32 direct, Z in-kernel
  gemm2f<<<4 * 16 * BATCH, 512, 135168, stream>>>(Q, KVt, out, Ksum);
}

// Round 9
// 148.094 us; speedup vs baseline: 1.6986x; 1.6986x over previous
//
#include <hip/hip_runtime.h>

#define BATCH 4
#define SEQ   4096
#define DIM   1024
#define EPS_F 1e-6f
#define KSPLIT 4

typedef __bf16 bf16_t;
typedef bf16_t bf16x8 __attribute__((ext_vector_type(8)));
typedef float  f32x4  __attribute__((ext_vector_type(4)));
typedef unsigned short u16x8 __attribute__((ext_vector_type(8)));

__device__ __forceinline__ unsigned short f2bf(float f) {
  unsigned u = __float_as_uint(f);
  u += 0x7FFFu + ((u >> 16) & 1u);          // round-to-nearest-even
  return (unsigned short)(u >> 16);
}
__device__ __forceinline__ float bf2f(unsigned short h) {
  return __uint_as_float(((unsigned)h) << 16);
}
__device__ __forceinline__ float phi_f(float x) {
  return x > 0.f ? x + 1.f : __expf(x);     // elu(x)+1
}

// ---- fused transpose: z<4 -> phi(K)^T + ksum; z>=4 -> V^T plain ----
__global__ __launch_bounds__(256) void phi_transpose_kv(
    const float* __restrict__ Kin, const float* __restrict__ Vin,
    unsigned short* __restrict__ Kt, unsigned short* __restrict__ Vt,
    float* __restrict__ ksum) {
  __shared__ float tl[32][33];
  __shared__ float ps[8][32];
  const int z = blockIdx.z;
  const bool isK = z < BATCH;
  const int b = isK ? z : z - BATCH;
  const float* in = isK ? Kin : Vin;
  unsigned short* out = isK ? Kt : Vt;
  const int bx = blockIdx.x * 32;          // col base
  const int by = blockIdx.y * 32;          // row base
  const size_t bo = (size_t)b * SEQ * DIM;
  const int x = threadIdx.x, y = threadIdx.y;
  #pragma unroll
  for (int j = 0; j < 32; j += 8) {
    float v = in[bo + (size_t)(by + y + j) * DIM + bx + x];
    if (isK) v = phi_f(v);
    tl[y + j][x] = v;
  }
  __syncthreads();
  #pragma unroll
  for (int j = 0; j < 32; j += 8)
    out[bo + (size_t)(bx + y + j) * SEQ + by + x] = f2bf(tl[x][y + j]);
  if (isK) {
    float s = tl[y][x] + tl[y + 8][x] + tl[y + 16][x] + tl[y + 24][x];
    ps[y][x] = s;
    __syncthreads();
    if (y == 0) {
      float tot = 0.f;
      #pragma unroll
      for (int j = 0; j < 8; ++j) tot += ps[j][x];
      atomicAdd(&ksum[(size_t)b * DIM + bx + x], tot);
    }
  }
}

// ---- phi(Q) cast + fused Z ----
__global__ __launch_bounds__(256) void phi_cast_qz(const float* __restrict__ Q,
    const float* __restrict__ Ksum, unsigned short* __restrict__ Qp,
    float* __restrict__ invZ) {
  const int row  = blockIdx.x * 4 + (threadIdx.x >> 6);   // b*SEQ + n
  const int lane = threadIdx.x & 63;
  const int b = row >> 12;
  const float* q  = Q + (size_t)row * DIM;
  const float* ks = Ksum + (size_t)b * DIM;
  float s = 0.f;
  #pragma unroll
  for (int c = 0; c < 2; ++c) {
    const int d0 = c * 512 + lane * 8;
    float4 v0 = *(const float4*)(q + d0);
    float4 v1 = *(const float4*)(q + d0 + 4);
    float4 k0 = *(const float4*)(ks + d0);
    float4 k1 = *(const float4*)(ks + d0 + 4);
    u16x8 o;
    o[0] = f2bf(phi_f(v0.x)); s += bf2f(o[0]) * k0.x;
    o[1] = f2bf(phi_f(v0.y)); s += bf2f(o[1]) * k0.y;
    o[2] = f2bf(phi_f(v0.z)); s += bf2f(o[2]) * k0.z;
    o[3] = f2bf(phi_f(v0.w)); s += bf2f(o[3]) * k0.w;
    o[4] = f2bf(phi_f(v1.x)); s += bf2f(o[4]) * k1.x;
    o[5] = f2bf(phi_f(v1.y)); s += bf2f(o[5]) * k1.y;
    o[6] = f2bf(phi_f(v1.z)); s += bf2f(o[6]) * k1.z;
    o[7] = f2bf(phi_f(v1.w)); s += bf2f(o[7]) * k1.w;
    *(u16x8*)(Qp + (size_t)row * DIM + d0) = o;
  }
  #pragma unroll
  for (int off = 32; off > 0; off >>= 1) s += __shfl_down(s, off);
  if (lane == 0) invZ[row] = 1.0f / (s + EPS_F);
}

// ---- reduce KSPLIT bf16 partials -> bf16 KVt ----
__global__ __launch_bounds__(256) void reduce_kv(const unsigned short* __restrict__ P,
    unsigned short* __restrict__ KVt) {
  const size_t per = (size_t)DIM * DIM;
  const size_t i = ((size_t)blockIdx.x * 256 + threadIdx.x) * 8;
  const size_t b = blockIdx.y;
  const unsigned short* p = P + b * KSPLIT * per + i;
  float s[8] = {};
  #pragma unroll
  for (int sp = 0; sp < KSPLIT; ++sp) {
    u16x8 v = *(const u16x8*)(p + sp * per);
    #pragma unroll
    for (int j = 0; j < 8; ++j) s[j] += bf2f(v[j]);
  }
  u16x8 o;
  #pragma unroll
  for (int j = 0; j < 8; ++j) o[j] = f2bf(s[j]);
  *(u16x8*)(KVt + b * per + i) = o;
}

// ======== 256x256 8-phase bt-GEMM (R5 structure, best measured) ============
// PRIO: wrap MFMA clusters in s_setprio (A/B: gemm1 on, gemm2 off).
#define GLD(gp, lp) __builtin_amdgcn_global_load_lds( \
    (const __attribute__((address_space(1))) unsigned int*)(gp), \
    (__attribute__((address_space(3))) unsigned int*)(lp), 16, 0, 0)
#define BARRIER __builtin_amdgcn_s_barrier()
#define WAITV(n) asm volatile("s_waitcnt vmcnt(" #n ")" ::: "memory")

template<int EPI, int KS, int NT, int PRIO>
__global__ __launch_bounds__(512, 2) void gemm256_bt(
    const unsigned short* __restrict__ A, const unsigned short* __restrict__ Bm,
    void* __restrict__ Cv, const float* __restrict__ invZ,
    int M, int Nc, int K, int gx, int gy) {
  extern __shared__ unsigned short lds[];
  unsigned short* const As0 = lds;
  unsigned short* const As1 = lds + 16384;
  unsigned short* const Bs0 = lds + 32768;
  unsigned short* const Bs1 = lds + 49152;

  const int t    = threadIdx.x;
  const int wid  = t >> 6;
  const int lane = t & 63;
  // XCD-chunked bijective swizzle (gridDim.x divisible by 8)
  const int id   = blockIdx.x;
  const int sw   = (id & 7) * (gridDim.x >> 3) + (id >> 3);
  const int bxi  = sw % gx;
  const int rem  = sw / gx;
  const int byi  = rem % gy;
  const int bz   = rem / gy;
  const int brow = byi * 256, bcol = bxi * 256;
  const size_t batch = bz / KS;
  const int split = bz % KS;
  const int Kc = K / KS;
  const unsigned short* Ab = A + batch * ((size_t)M * K) + (size_t)brow * K + (size_t)split * Kc;
  const unsigned short* Bb = Bm + batch * ((size_t)Nc * K) + (size_t)bcol * K + (size_t)split * Kc;

  const int srow_t = t >> 3;
  const int c_src  = (t & 7) ^ (srow_t & 7);
  const unsigned short* gA = Ab + (size_t)srow_t * K + c_src * 8;
  const unsigned short* gB = Bb + (size_t)((srow_t >> 5) * 64 + (srow_t & 31)) * K + c_src * 8;
  const int ldsAu = wid * 512;
  const int ldsBu = wid * 512 + (wid >> 2) * 2048;

  auto stageA = [&](unsigned short* D, int h, int kt) {
    GLD(gA + (size_t)(h * 64) * K + (size_t)kt * 64,       D + (h * 64) * 64 + ldsAu);
    GLD(gA + (size_t)(128 + h * 64) * K + (size_t)kt * 64, D + (128 + h * 64) * 64 + ldsAu);
  };
  auto stageB = [&](unsigned short* D, int h, int kt) {
    GLD(gB + (size_t)(h * 32) * K + (size_t)kt * 64,       D + (h * 32) * 64 + ldsBu);
    GLD(gB + (size_t)(128 + h * 32) * K + (size_t)kt * 64, D + (128 + h * 32) * 64 + ldsBu);
  };

  const int fr  = lane & 15;
  const int g   = lane >> 4;
  const int wrw = (wid >> 2) * 128;
  const int wcw = (wid & 3) * 64;
  const int ck0 = ((g)     ^ (fr & 7)) * 8;
  const int ck1 = ((4 + g) ^ (fr & 7)) * 8;

  f32x4 acc[8][4] = {};
  bf16x8 afX[4][2], afY[4][2], bfX[2][2], bfY[2][2];

#define LDA(S, mh, DST) { _Pragma("unroll") for (int m_ = 0; m_ < 4; ++m_) { \
    const int ro_ = (wrw + ((mh) * 4 + m_) * 16 + fr) * 64; \
    DST[m_][0] = *(const bf16x8*)((S) + ro_ + ck0); \
    DST[m_][1] = *(const bf16x8*)((S) + ro_ + ck1); } }
#define LDBF(S, nh, DST) { _Pragma("unroll") for (int n_ = 0; n_ < 2; ++n_) { \
    const int ro_ = (wcw + (nh) * 32 + n_ * 16 + fr) * 64; \
    DST[n_][0] = *(const bf16x8*)((S) + ro_ + ck0); \
    DST[n_][1] = *(const bf16x8*)((S) + ro_ + ck1); } }
#define MM(mh, nh, AF, BF) { if (PRIO) __builtin_amdgcn_s_setprio(1); \
    _Pragma("unroll") for (int m_ = 0; m_ < 4; ++m_) \
    _Pragma("unroll") for (int n_ = 0; n_ < 2; ++n_) \
    _Pragma("unroll") for (int k_ = 0; k_ < 2; ++k_) \
      acc[(mh) * 4 + m_][(nh) * 2 + n_] = __builtin_amdgcn_mfma_f32_16x16x32_bf16( \
          AF[m_][k_], BF[n_][k_], acc[(mh) * 4 + m_][(nh) * 2 + n_], 0, 0, 0); \
    if (PRIO) __builtin_amdgcn_s_setprio(0); }

  unsigned short *Ac = As0, *An = As1, *Bc = Bs0, *Bn = Bs1;

  // prologue: stage tiles 0 and 1 fully; wait tile 0; preload first operands
  stageA(Ac, 0, 0); stageB(Bc, 0, 0); stageB(Bc, 1, 0); stageA(Ac, 1, 0);
  stageA(An, 0, 1); stageB(Bn, 0, 1); stageB(Bn, 1, 1);
  stageA(An, 1, 1);
  WAITV(8);
  BARRIER;
  LDA(Ac, 0, afX); LDBF(Bc, 0, bfX);

  #pragma unroll 1
  for (int it = 0; it < NT - 2; ++it) {
    const int t2 = it + 2;
    LDBF(Bc, 1, bfY);
    stageA(Ac, 0, t2);
    BARRIER; MM(0, 0, afX, bfX); BARRIER;
    stageB(Bc, 0, t2);
    WAITV(6);
    BARRIER;
    LDA(Ac, 1, afY);
    MM(0, 1, afX, bfY); BARRIER;
    LDA(An, 0, afX);
    stageB(Bc, 1, t2);
    BARRIER; MM(1, 0, afY, bfX); BARRIER;
    LDBF(Bn, 0, bfX);
    stageA(Ac, 1, t2);
    BARRIER; MM(1, 1, afY, bfY); BARRIER;
    unsigned short* tp;
    tp = Ac; Ac = An; An = tp;
    tp = Bc; Bc = Bn; Bn = tp;
  }
  // tail tile NT-2: no staging; drain all loads
  LDBF(Bc, 1, bfY);
  BARRIER; MM(0, 0, afX, bfX); BARRIER;
  WAITV(0);
  BARRIER;
  LDA(Ac, 1, afY);
  MM(0, 1, afX, bfY); BARRIER;
  LDA(An, 0, afX);
  BARRIER; MM(1, 0, afY, bfX); BARRIER;
  LDBF(Bn, 0, bfX);
  BARRIER; MM(1, 1, afY, bfY); BARRIER;
  {
    unsigned short* tp;
    tp = Ac; Ac = An; An = tp;
    tp = Bc; Bc = Bn; Bn = tp;
  }
  // tail tile NT-1
  LDBF(Bc, 1, bfY);
  BARRIER; MM(0, 0, afX, bfX);
  LDA(Ac, 1, afY);
  MM(0, 1, afX, bfY);
  MM(1, 0, afY, bfX);
  MM(1, 1, afY, bfY);
#undef LDA
#undef LDBF
#undef MM

  // epilogue: C/D layout col=fr, row=g*4+r per 16x16 fragment
  if (EPI == 0) {
    unsigned short* Cb = (unsigned short*)Cv + (size_t)bz * M * Nc;
    #pragma unroll
    for (int m = 0; m < 8; ++m) {
      const int row = brow + wrw + m * 16 + g * 4;
      #pragma unroll
      for (int r = 0; r < 4; ++r)
        #pragma unroll
        for (int n = 0; n < 4; ++n)
          Cb[(size_t)(row + r) * Nc + bcol + wcw + n * 16 + fr] = f2bf(acc[m][n][r]);
    }
  } else {
    float* Cb = (float*)Cv + batch * ((size_t)M * Nc);
    const float* zb = invZ + batch * (size_t)M;
    #pragma unroll
    for (int m = 0; m < 8; ++m) {
      const int row = brow + wrw + m * 16 + g * 4;
      #pragma unroll
      for (int r = 0; r < 4; ++r) {
        const float z = zb[row + r];
        #pragma unroll
        for (int n = 0; n < 4; ++n)
          Cb[(size_t)(row + r) * Nc + bcol + wcw + n * 16 + fr] = acc[m][n][r] * z;
      }
    }
  }
}

extern "C" void kernel_launch(void* const* d_in, const int* in_sizes, int n_in,
                              void* d_out, int out_size, void* d_ws, size_t ws_size,
                              hipStream_t stream) {
  const float* Q = (const float*)d_in[0];
  const float* K = (const float*)d_in[1];
  const float* V = (const float*)d_in[2];
  float* out = (float*)d_out;

  char* ws = (char*)d_ws;
  size_t off = 0;
  auto alloc = [&](size_t bytes) {
    void* p = ws + off;
    off += (bytes + 255) & ~(size_t)255;
    return p;
  };
  // Qp region doubles as split-K partial buffer P (both 32 MB):
  // gemm1 writes P -> reduce reads P -> phi_cast_qz overwrites as Qp.
  unsigned short* Qp   = (unsigned short*)alloc((size_t)BATCH * SEQ * DIM * 2);
  unsigned short* P    = Qp;
  unsigned short* Kt   = (unsigned short*)alloc((size_t)BATCH * SEQ * DIM * 2);
  unsigned short* Vt   = (unsigned short*)alloc((size_t)BATCH * SEQ * DIM * 2);
  unsigned short* KVt  = (unsigned short*)alloc((size_t)BATCH * DIM * DIM * 2);
  float* Ksum = (float*)alloc((size_t)BATCH * DIM * 4);
  float* invZ = (float*)alloc((size_t)BATCH * SEQ * 4);

  hipFuncSetAttribute(reinterpret_cast<const void*>(&gemm256_bt<0, KSPLIT, 16, 1>),
                      hipFuncAttributeMaxDynamicSharedMemorySize, 131072);
  hipFuncSetAttribute(reinterpret_cast<const void*>(&gemm256_bt<1, 1, 16, 0>),
                      hipFuncAttributeMaxDynamicSharedMemorySize, 131072);

  // Ksum = 0 (async memset node; graph-capturable)
  hipMemsetAsync(Ksum, 0, (size_t)BATCH * DIM * 4, stream);
  // fused phi(K)^T+ksum and V^T in one dispatch
  phi_transpose_kv<<<dim3(DIM / 32, SEQ / 32, 2 * BATCH), dim3(32, 8), 0, stream>>>(
      K, V, Kt, Vt, Ksum);
  // gemm1 split-K: P[b][s] = Vt * Kt^T over n-split s  (M=Nc=1024, Kc=1024 -> NT=16)
  gemm256_bt<0, KSPLIT, 16, 1><<<(DIM / 256) * (DIM / 256) * BATCH * KSPLIT, 512, 131072, stream>>>(
      Vt, Kt, P, nullptr, DIM, DIM, SEQ, DIM / 256, DIM / 256);
  // KVt = sum_s P[s]
  reduce_kv<<<dim3(DIM * DIM / (256 * 8), BATCH), 256, 0, stream>>>(P, KVt);
  // phi(Q) cast + fused Z (after reduce: overwrites P region)
  phi_cast_qz<<<BATCH * SEQ / 4, 256, 0, stream>>>(Q, Ksum, Qp, invZ);
  // gemm2: out = (Qp * KVt^T) * invZ  (M=4096, Nc=1024, K=1024 -> NT=16; PRIO off A/B)
  gemm256_bt<1, 1, 16, 0><<<(DIM / 256) * (SEQ / 256) * BATCH, 512, 131072, stream>>>(
      Qp, KVt, out, invZ, SEQ, DIM, DIM, DIM / 256, SEQ / 256);
}